// Round 12
// baseline (17724.800 us; speedup 1.0000x reference)
//
#include <hip/hip_runtime.h>

// ---------------------------------------------------------------------------
// RNN attention decoder (GRU x2 + general attention + generator), MI355X.
// Round 12:
//   - decode loop: PERSISTENT kernel (512 blocks, proven co-resident in r8)
//     with hand-rolled device-scope barrier (threadfence + atomic add +
//     relaxed-load spin w/ s_sleep).  Phase math/plane layout identical to
//     the passing round-11 multi-launch version -> bit-identical output.
//   - generator: reverted to round-9 exact config (mt-major, cached stores,
//     XCD swizzle; NT stores regressed: finer-granule HBM writes).
// Precision (verified round 6): split-bf16 hi/lo 3-term K-concat on all
// recurrence/attention GEMMs; plain bf16 generator.
// ---------------------------------------------------------------------------

using u16 = unsigned short;
typedef __attribute__((ext_vector_type(4))) float f32x4;
typedef __attribute__((ext_vector_type(4))) u16 u16x4;
typedef __attribute__((ext_vector_type(8))) u16 u16x8;
typedef __attribute__((ext_vector_type(8))) __bf16 bf16x8;

#define DEVFN static __device__ __forceinline__

DEVFN u16 f2bf(float f) {
  unsigned u = __float_as_uint(f);
  return (u16)((u + 0x7FFFu + ((u >> 16) & 1u)) >> 16);
}
DEVFN float bf2f(u16 h) { return __uint_as_float(((unsigned)h) << 16); }
DEVFN float sigm(float x) { return 1.0f / (1.0f + expf(-x)); }
DEVFN float gru_gate(float ir, float iz, float inn,
                     float hr, float hz, float hn, float hprev) {
  float r = sigm(ir + hr);
  float z = sigm(iz + hz);
  float n = tanhf(inn + r * hn);
  return (1.0f - z) * n + z * hprev;
}

// ---------------------------------------------------------------------------
// Full-K GEMM C = A * B^T (prologue / generator), round-9 form (mt-major).
// ---------------------------------------------------------------------------
struct GemmB3 {
  const u16* A[3];
  const u16* B[3];
  void* C[3];
  int ldb[3];
};

template <int BM, int BN, int OUTMODE, bool BIAS>
__global__ __launch_bounds__(256) void gemm_bt(
    GemmB3 args, int lda, int ldc, int Ntiles, int K,
    const float* __restrict__ bias, int swz) {
  constexpr int MF = BM / 32;
  constexpr int NF = BN / 32;
  constexpr int IA = (BM * 8) / 256;
  constexpr int IB = (BN * 8) / 256;
  __shared__ alignas(16) u16 lsA[BM * 64];
  __shared__ alignas(16) u16 lsB[BN * 64];

  const int g = blockIdx.y;
  int bx = blockIdx.x;
  if (swz) bx = (bx & 7) * ((int)gridDim.x >> 3) + (bx >> 3);
  const int mt = bx / Ntiles;
  const int nt = bx - mt * Ntiles;
  const int tid = threadIdx.x;
  const int lane = tid & 63;
  const int wv = tid >> 6;
  const int wr = wv >> 1, wc = wv & 1;
  const int l15 = lane & 15, l4 = lane >> 4;
  const int ldb = args.ldb[g];
  const u16* __restrict__ Ag = args.A[g] + (size_t)mt * BM * lda;
  const u16* __restrict__ Bg = args.B[g] + (size_t)nt * BN * ldb;

  f32x4 acc[MF][NF];
#pragma unroll
  for (int m = 0; m < MF; ++m)
#pragma unroll
    for (int n = 0; n < NF; ++n) acc[m][n] = f32x4{0.f, 0.f, 0.f, 0.f};

  const int KT = K >> 6;
  for (int kt = 0; kt < KT; ++kt) {
#pragma unroll
    for (int i = 0; i < IA; ++i) {
      const int chunk = i * 256 + tid;
      const int row = chunk >> 3, c8 = chunk & 7;
      const int cs = c8 ^ (row & 7);
      u16x8 v = *reinterpret_cast<const u16x8*>(
          Ag + (size_t)row * lda + (kt * 64 + c8 * 8));
      *reinterpret_cast<u16x8*>(lsA + row * 64 + cs * 8) = v;
    }
#pragma unroll
    for (int i = 0; i < IB; ++i) {
      const int chunk = i * 256 + tid;
      const int row = chunk >> 3, c8 = chunk & 7;
      const int cs = c8 ^ (row & 7);
      u16x8 v = *reinterpret_cast<const u16x8*>(
          Bg + (size_t)row * ldb + (kt * 64 + c8 * 8));
      *reinterpret_cast<u16x8*>(lsB + row * 64 + cs * 8) = v;
    }
    __syncthreads();
#pragma unroll
    for (int ks = 0; ks < 2; ++ks) {
      bf16x8 av[MF], bv[NF];
#pragma unroll
      for (int m = 0; m < MF; ++m) {
        const int row = wr * (BM / 2) + m * 16 + l15;
        const int cc = (ks * 4 + l4) ^ (row & 7);
        av[m] = *reinterpret_cast<const bf16x8*>(lsA + row * 64 + cc * 8);
      }
#pragma unroll
      for (int n = 0; n < NF; ++n) {
        const int row = wc * (BN / 2) + n * 16 + l15;
        const int cc = (ks * 4 + l4) ^ (row & 7);
        bv[n] = *reinterpret_cast<const bf16x8*>(lsB + row * 64 + cc * 8);
      }
#pragma unroll
      for (int m = 0; m < MF; ++m)
#pragma unroll
        for (int n = 0; n < NF; ++n)
          acc[m][n] = __builtin_amdgcn_mfma_f32_16x16x32_bf16(
              av[m], bv[n], acc[m][n], 0, 0, 0);
    }
    __syncthreads();
  }

#pragma unroll
  for (int m = 0; m < MF; ++m) {
    const int grow = mt * BM + wr * (BM / 2) + m * 16 + l4 * 4;
#pragma unroll
    for (int n = 0; n < NF; ++n) {
      const int gcol = nt * BN + wc * (BN / 2) + n * 16 + l15;
      const float bsv = BIAS ? bias[gcol] : 0.f;
#pragma unroll
      for (int j = 0; j < 4; ++j) {
        const float v = acc[m][n][j] + bsv;
        const size_t idx = (size_t)(grow + j) * ldc + gcol;
        if constexpr (OUTMODE == 0) {
          ((float*)args.C[g])[idx] = v;
        } else {
          ((u16*)args.C[g])[idx] = f2bf(v);
        }
      }
    }
  }
}

// ---------------------------------------------------------------------------
// Device GEMM tile: C = A*B^T over K-tile range [kt0, kt0+nkt), f32 out.
// (verbatim from the round-8 passing cooperative kernel)
// ---------------------------------------------------------------------------
template <int BM, int BN>
DEVFN void gemm_tile_dev(const u16* __restrict__ Atile, int lda,
                         const u16* __restrict__ Btile, int ldb,
                         float* __restrict__ Ctile, int ldc, int kt0, int nkt,
                         u16* lsA, u16* lsB, int tid) {
  constexpr int MF = BM / 32;
  constexpr int NF = BN / 32;
  constexpr int IA = (BM * 8) / 256;
  constexpr int IB = (BN * 8) / 256;
  const int lane = tid & 63;
  const int wv = tid >> 6;
  const int wr = wv >> 1, wc = wv & 1;
  const int l15 = lane & 15, l4 = lane >> 4;

  f32x4 acc[MF][NF];
#pragma unroll
  for (int m = 0; m < MF; ++m)
#pragma unroll
    for (int n = 0; n < NF; ++n) acc[m][n] = f32x4{0.f, 0.f, 0.f, 0.f};

  for (int kk = 0; kk < nkt; ++kk) {
    const int kt = kt0 + kk;
#pragma unroll
    for (int i = 0; i < IA; ++i) {
      const int chunk = i * 256 + tid;
      const int row = chunk >> 3, c8 = chunk & 7;
      const int cs = c8 ^ (row & 7);
      u16x8 v = *reinterpret_cast<const u16x8*>(
          Atile + (size_t)row * lda + (kt * 64 + c8 * 8));
      *reinterpret_cast<u16x8*>(lsA + row * 64 + cs * 8) = v;
    }
#pragma unroll
    for (int i = 0; i < IB; ++i) {
      const int chunk = i * 256 + tid;
      const int row = chunk >> 3, c8 = chunk & 7;
      const int cs = c8 ^ (row & 7);
      u16x8 v = *reinterpret_cast<const u16x8*>(
          Btile + (size_t)row * ldb + (kt * 64 + c8 * 8));
      *reinterpret_cast<u16x8*>(lsB + row * 64 + cs * 8) = v;
    }
    __syncthreads();
#pragma unroll
    for (int k2 = 0; k2 < 2; ++k2) {
      bf16x8 av[MF], bv[NF];
#pragma unroll
      for (int m = 0; m < MF; ++m) {
        const int row = wr * (BM / 2) + m * 16 + l15;
        const int cc = (k2 * 4 + l4) ^ (row & 7);
        av[m] = *reinterpret_cast<const bf16x8*>(lsA + row * 64 + cc * 8);
      }
#pragma unroll
      for (int n = 0; n < NF; ++n) {
        const int row = wc * (BN / 2) + n * 16 + l15;
        const int cc = (k2 * 4 + l4) ^ (row & 7);
        bv[n] = *reinterpret_cast<const bf16x8*>(lsB + row * 64 + cc * 8);
      }
#pragma unroll
      for (int m = 0; m < MF; ++m)
#pragma unroll
        for (int n = 0; n < NF; ++n)
          acc[m][n] = __builtin_amdgcn_mfma_f32_16x16x32_bf16(
              av[m], bv[n], acc[m][n], 0, 0, 0);
    }
    __syncthreads();
  }

#pragma unroll
  for (int m = 0; m < MF; ++m) {
    const int row = wr * (BM / 2) + m * 16 + l4 * 4;
#pragma unroll
    for (int n = 0; n < NF; ++n) {
      const int col = wc * (BN / 2) + n * 16 + l15;
#pragma unroll
      for (int j = 0; j < 4; ++j)
        Ctile[(size_t)(row + j) * ldc + col] = acc[m][n][j];
    }
  }
}

// standalone K-split partial GEMM (prologue G0h(0) seed)
struct GemmP {
  const u16* A[3];
  const u16* B[3];
  float* C[3];
};

template <int BM, int BN>
__global__ __launch_bounds__(256) void gemm_part(
    GemmP args, int lda, int ldb, int N, int Ntiles, int KS, int nkt,
    int Mrows) {
  __shared__ alignas(16) u16 lsA[BM * 64];
  __shared__ alignas(16) u16 lsB[BN * 64];
  const int g = blockIdx.y;
  const int bx = blockIdx.x;
  const int tile = bx / KS;
  const int ks = bx - tile * KS;
  const int mt = tile / Ntiles;
  const int nt = tile - mt * Ntiles;
  gemm_tile_dev<BM, BN>(
      args.A[g] + (size_t)mt * BM * lda, lda,
      args.B[g] + (size_t)nt * BN * ldb, ldb,
      args.C[g] + (size_t)ks * Mrows * N + (size_t)mt * BM * N + nt * BN, N,
      ks * nkt, nkt, lsA, lsB, threadIdx.x);
}

// ---------------------------------------------------------------------------
// Persistent decode loop with hand-rolled device-scope barrier.
// ---------------------------------------------------------------------------
DEVFN void gridbar(unsigned* cnt, unsigned* genp) {
  __syncthreads();
  if (threadIdx.x == 0) {
    __threadfence();  // release: writeback XCD L2
    const unsigned target = (++(*genp)) * 512u;
    __hip_atomic_fetch_add(cnt, 1u, __ATOMIC_RELEASE,
                           __HIP_MEMORY_SCOPE_AGENT);
    while (__hip_atomic_load(cnt, __ATOMIC_RELAXED,
                             __HIP_MEMORY_SCOPE_AGENT) < target)
      __builtin_amdgcn_s_sleep(8);
    __threadfence();  // acquire: invalidate caches
  }
  __syncthreads();
}

struct PK {
  u16 *out3, *h0a3, *h1a3, *cat3, *outall;
  float *h0f, *h1f, *outf;
  const u16 *gi0, *W0ihO3, *W0hh3, *W1hh3, *W1ih3, *Wc3;
  const float *ctxWa, *ctxf;
  const float *bhh0, *bih1, *bhh1;
  float *Ppart;   // planes: 0-5 P, 6-11 G0h, 12-17 G1h (each 128*3072 f32)
  float *G1ip;    // planes 0-5
  float *Wcpart;  // planes 0-15 (each 128*1024 f32)
  unsigned* bar;
};

__global__ __launch_bounds__(256, 2) void decode_pk(PK a) {
  __shared__ alignas(16) u16 lsA[128 * 64];
  __shared__ alignas(16) u16 lsB[64 * 64];
  __shared__ float sh1[1024];
  __shared__ float red[256];
  __shared__ float ssc[64];
  const int bid = blockIdx.x;
  const int tid = threadIdx.x;
  unsigned gen = 0;

  for (int t = 0; t < 32; ++t) {
    // ---- P1: {P(t): out3@W0ihO3 -> planes 0-5, G1h(t): h1a3@W1hh3 -> 12-17}
    for (int job = bid; job < 576; job += 512) {
      const int g = job / 288;
      const int rem = job - g * 288;
      const int nt = rem / 6, ks = rem - nt * 6;
      const u16* Ap = (g == 0) ? a.out3 : a.h1a3;
      const u16* Bp = (g == 0) ? a.W0ihO3 : a.W1hh3;
      float* Cp = a.Ppart + (size_t)((g == 0 ? 0 : 12) + ks) * 393216 + nt * 64;
      gemm_tile_dev<128, 64>(Ap, 3072, Bp + (size_t)nt * 64 * 3072, 3072, Cp,
                             3072, ks * 8, 8, lsA, lsB, tid);
    }
    gridbar(a.bar, &gen);

    // ---- P2: gate0 -> h0 (1 elem/thread) --------------------------------
    {
      const int i = bid * 256 + tid;  // 512*256 == 131072
      const int b = i >> 10, c = i & 1023;
      const size_t r3 = (size_t)b * 3072;
      float pr = 0.f, pz = 0.f, pn = 0.f, qr = 0.f, qz = 0.f, qn = 0.f;
#pragma unroll
      for (int ks = 0; ks < 6; ++ks) {
        const float* P0 = a.Ppart + (size_t)ks * 393216 + r3;
        const float* P1 = a.Ppart + (size_t)(6 + ks) * 393216 + r3;
        pr += P0[c]; pz += P0[1024 + c]; pn += P0[2048 + c];
        qr += P1[c]; qz += P1[1024 + c]; qn += P1[2048 + c];
      }
      const u16* gi = a.gi0 + (size_t)t * 393216 + r3;
      const float h0 = gru_gate(
          bf2f(gi[c]) + pr, bf2f(gi[1024 + c]) + pz, bf2f(gi[2048 + c]) + pn,
          qr + a.bhh0[c], qz + a.bhh0[1024 + c], qn + a.bhh0[2048 + c],
          a.h0f[i]);
      a.h0f[i] = h0;
      const u16 hb = f2bf(h0);
      const u16 lb = f2bf(h0 - bf2f(hb));
      a.h0a3[r3 + c] = hb;
      a.h0a3[r3 + 1024 + c] = lb;
      a.h0a3[r3 + 2048 + c] = hb;
    }
    gridbar(a.bar, &gen);

    // ---- P3: {G1i(t): h0a3@W1ih3 -> G1ip, G0h(t+1): h0a3@W0hh3 -> 6-11} --
    for (int job = bid; job < 576; job += 512) {
      const int g = job / 288;
      const int rem = job - g * 288;
      const int nt = rem / 6, ks = rem - nt * 6;
      const u16* Bp = (g == 0) ? a.W1ih3 : a.W0hh3;
      float* Cp = (g == 0) ? (a.G1ip + (size_t)ks * 393216 + nt * 64)
                           : (a.Ppart + (size_t)(6 + ks) * 393216 + nt * 64);
      gemm_tile_dev<128, 64>(a.h0a3, 3072, Bp + (size_t)nt * 64 * 3072, 3072,
                             Cp, 3072, ks * 8, 8, lsA, lsB, tid);
    }
    gridbar(a.bar, &gen);

    // ---- P4: GRU1 gate + attention (one block per batch b) ---------------
    if (bid < 128) {
      const int b = bid;
      const int k = tid * 4;
      const size_t r3 = (size_t)b * 3072;
      const size_t r1 = (size_t)b * 1024;
      u16* catr = a.cat3 + (size_t)b * 6144;
      {
        f32x4 ir = {0.f, 0.f, 0.f, 0.f}, iz = ir, in_ = ir;
        f32x4 hr = ir, hz = ir, hn = ir;
#pragma unroll
        for (int ks = 0; ks < 6; ++ks) {
          const float* gi = a.G1ip + (size_t)ks * 393216 + r3;
          const float* gh = a.Ppart + (size_t)(12 + ks) * 393216 + r3;
          ir += *(const f32x4*)(gi + k);
          iz += *(const f32x4*)(gi + 1024 + k);
          in_ += *(const f32x4*)(gi + 2048 + k);
          hr += *(const f32x4*)(gh + k);
          hz += *(const f32x4*)(gh + 1024 + k);
          hn += *(const f32x4*)(gh + 2048 + k);
        }
        f32x4 bir = *(const f32x4*)(a.bih1 + k);
        f32x4 biz = *(const f32x4*)(a.bih1 + 1024 + k);
        f32x4 bin_ = *(const f32x4*)(a.bih1 + 2048 + k);
        f32x4 bhr = *(const f32x4*)(a.bhh1 + k);
        f32x4 bhz = *(const f32x4*)(a.bhh1 + 1024 + k);
        f32x4 bhn = *(const f32x4*)(a.bhh1 + 2048 + k);
        f32x4 hp = *(const f32x4*)(a.h1f + r1 + k);
        f32x4 hnew;
        u16x4 hb, lb;
#pragma unroll
        for (int j = 0; j < 4; ++j) {
          hnew[j] =
              gru_gate(ir[j] + bir[j], iz[j] + biz[j], in_[j] + bin_[j],
                       hr[j] + bhr[j], hz[j] + bhz[j], hn[j] + bhn[j], hp[j]);
          sh1[k + j] = hnew[j];
          hb[j] = f2bf(hnew[j]);
          lb[j] = f2bf(hnew[j] - bf2f(hb[j]));
        }
        *(f32x4*)(a.h1f + r1 + k) = hnew;
        *(u16x4*)(a.h1a3 + r3 + k) = hb;
        *(u16x4*)(a.h1a3 + r3 + 1024 + k) = lb;
        *(u16x4*)(a.h1a3 + r3 + 2048 + k) = hb;
        *(u16x4*)(catr + 1024 + k) = hb;
        *(u16x4*)(catr + 2048 + 1024 + k) = lb;
        *(u16x4*)(catr + 4096 + 1024 + k) = hb;
      }
      __syncthreads();
      const int s = tid >> 2, part = tid & 3;
      {
        const float* cw = a.ctxWa + ((size_t)b * 64 + s) * 1024 + part * 256;
        const float* hh = sh1 + part * 256;
        float p = 0.f;
        for (int i = 0; i < 256; i += 4) {
          f32x4 v = *(const f32x4*)(cw + i);
          p += v[0] * hh[i] + v[1] * hh[i + 1] + v[2] * hh[i + 2] +
               v[3] * hh[i + 3];
        }
        red[tid] = p;
      }
      __syncthreads();
      if (part == 0)
        ssc[s] = red[tid] + red[tid + 1] + red[tid + 2] + red[tid + 3];
      __syncthreads();
      if (tid == 0) {
        float mx = -1e30f;
        for (int i = 0; i < 64; ++i) mx = fmaxf(mx, ssc[i]);
        float sm = 0.f;
        for (int i = 0; i < 64; ++i) {
          float e = expf(ssc[i] - mx);
          ssc[i] = e;
          sm += e;
        }
        const float inv = 1.0f / sm;
        for (int i = 0; i < 64; ++i) ssc[i] *= inv;
      }
      __syncthreads();
      {
        float a0 = 0.f, a1 = 0.f, a2 = 0.f, a3 = 0.f;
        const float* cb = a.ctxf + (size_t)b * 65536 + k;
        for (int s2 = 0; s2 < 64; ++s2) {
          const float w = ssc[s2];
          f32x4 v = *(const f32x4*)(cb + (size_t)s2 * 1024);
          a0 += w * v[0]; a1 += w * v[1]; a2 += w * v[2]; a3 += w * v[3];
        }
        f32x4 cv{a0, a1, a2, a3};
        u16x4 ch, cl;
#pragma unroll
        for (int j = 0; j < 4; ++j) {
          ch[j] = f2bf(cv[j]);
          cl[j] = f2bf(cv[j] - bf2f(ch[j]));
        }
        *(u16x4*)(catr + k) = ch;
        *(u16x4*)(catr + 2048 + k) = cl;
        *(u16x4*)(catr + 4096 + k) = ch;
      }
    }
    gridbar(a.bar, &gen);

    // ---- P5: Wc(t): cat3@Wc3, 32 tiles x 16 ks (512 jobs exactly) --------
    {
      const int job = bid;
      const int tile = job >> 4, ks = job & 15;
      const int mt = tile >> 4, nt = tile & 15;
      float* Cp = a.Wcpart + (size_t)ks * 131072 + (size_t)mt * 64 * 1024 +
                  nt * 64;
      gemm_tile_dev<64, 64>(a.cat3 + (size_t)mt * 64 * 6144, 6144,
                            a.Wc3 + (size_t)nt * 64 * 6144, 6144, Cp, 1024,
                            ks * 6, 6, lsA, lsB, tid);
    }
    gridbar(a.bar, &gen);

    // ---- P6: reduce 16 partials + tanh -> out ----------------------------
    {
      const int i = bid * 256 + tid;  // 131072
      const int b = i >> 10, c = i & 1023;
      float v = 0.f;
#pragma unroll
      for (int ks = 0; ks < 16; ++ks) v += a.Wcpart[(size_t)ks * 131072 + i];
      const float o = tanhf(v);
      a.outf[i] = o;
      a.outall[(size_t)t * 131072 + i] = f2bf(o);
      const u16 hb = f2bf(o);
      const u16 lb = f2bf(o - bf2f(hb));
      u16* d = a.out3 + (size_t)b * 3072;
      d[c] = hb;
      d[1024 + c] = lb;
      d[2048 + c] = hb;
    }
    gridbar(a.bar, &gen);
  }
}

// ---------------------------------------------------------------------------
// prologue helpers
// ---------------------------------------------------------------------------
__global__ __launch_bounds__(256) void cvt_bf16_vec(
    const float* __restrict__ in, u16* __restrict__ out, int n4) {
  int i = blockIdx.x * 256 + threadIdx.x;
  const int stride = gridDim.x * 256;
  for (; i < n4; i += stride) {
    f32x4 v = ((const f32x4*)in)[i];
    u16x4 o;
    o[0] = f2bf(v[0]); o[1] = f2bf(v[1]); o[2] = f2bf(v[2]); o[3] = f2bf(v[3]);
    ((u16x4*)out)[i] = o;
  }
}

__global__ __launch_bounds__(256) void split3_w4(
    const float* __restrict__ W0ih, const float* __restrict__ W0hh,
    const float* __restrict__ W1ih, const float* __restrict__ W1hh,
    u16* __restrict__ W0ihO3, u16* __restrict__ W0hh3,
    u16* __restrict__ W1ih3, u16* __restrict__ W1hh3) {
  const int g = blockIdx.y;
  const int idx = blockIdx.x * 256 + threadIdx.x;  // 3145728
  const int r = idx >> 10, c = idx & 1023;
  const float* src;
  int ld, ofs;
  u16* dst;
  if (g == 0) { src = W0ih; ld = 1600; ofs = 576; dst = W0ihO3; }
  else if (g == 1) { src = W0hh; ld = 1024; ofs = 0; dst = W0hh3; }
  else if (g == 2) { src = W1ih; ld = 1024; ofs = 0; dst = W1ih3; }
  else { src = W1hh; ld = 1024; ofs = 0; dst = W1hh3; }
  const float x = src[(size_t)r * ld + ofs + c];
  const u16 hi = f2bf(x);
  const u16 lo = f2bf(x - bf2f(hi));
  u16* d = dst + (size_t)r * 3072;
  d[c] = hi;
  d[1024 + c] = hi;
  d[2048 + c] = lo;
}

template <bool BSIDE>
__global__ __launch_bounds__(256) void split3(
    const float* __restrict__ src, int src_ld, int src_ofs,
    u16* __restrict__ dst, int C, int total) {
  const int idx = blockIdx.x * 256 + threadIdx.x;
  if (idx >= total) return;
  const int r = idx / C, c = idx - r * C;
  const float x = src[(size_t)r * src_ld + src_ofs + c];
  const u16 hi = f2bf(x);
  const u16 lo = f2bf(x - bf2f(hi));
  u16* d = dst + (size_t)r * (3 * C);
  d[c] = hi;
  d[C + c] = BSIDE ? hi : lo;
  d[2 * C + c] = BSIDE ? lo : hi;
}

__global__ __launch_bounds__(256) void transpose_split3(
    const float* __restrict__ Wa, u16* __restrict__ dst) {
  const int idx = blockIdx.x * 256 + threadIdx.x;
  const int i = idx >> 10, j = idx & 1023;
  const float x = Wa[idx];
  const u16 hi = f2bf(x);
  const u16 lo = f2bf(x - bf2f(hi));
  u16* d = dst + (size_t)j * 3072;
  d[i] = hi;
  d[1024 + i] = hi;
  d[2048 + i] = lo;
}

__global__ __launch_bounds__(256) void gather_emb(
    const int* __restrict__ wid, const int* __restrict__ fid,
    const float* __restrict__ wtab, const float* __restrict__ ftab,
    u16* __restrict__ Xwf) {
  const int r = blockIdx.x;
  const int w = wid[r], f = fid[r];
  u16* dst = Xwf + (size_t)r * 576;
  const float* wsrc = wtab + (size_t)w * 512;
  const float* fsrc = ftab + (size_t)f * 64;
  for (int c = threadIdx.x; c < 512; c += 256) dst[c] = f2bf(wsrc[c]);
  if (threadIdx.x < 64) dst[512 + threadIdx.x] = f2bf(fsrc[threadIdx.x]);
}

DEVFN void trip_store(u16* base3, int c, float x) {
  const u16 hi = f2bf(x);
  const u16 lo = f2bf(x - bf2f(hi));
  base3[c] = hi;
  base3[1024 + c] = lo;
  base3[2048 + c] = hi;
}

__global__ __launch_bounds__(256) void init_state(
    const float* __restrict__ hidden, const float* __restrict__ prev_out,
    float* __restrict__ h0f, float* __restrict__ h1f,
    u16* __restrict__ h0a3, u16* __restrict__ h1a3, u16* __restrict__ out3) {
  const int i = blockIdx.x * 256 + threadIdx.x;
  const int b = i >> 10, c = i & 1023;
  const float aa = hidden[i], bb = hidden[131072 + i], po = prev_out[i];
  h0f[i] = aa;
  h1f[i] = bb;
  trip_store(h0a3 + (size_t)b * 3072, c, aa);
  trip_store(h1a3 + (size_t)b * 3072, c, bb);
  trip_store(out3 + (size_t)b * 3072, c, po);
}

__global__ __launch_bounds__(256) void final_copy(
    const float* __restrict__ h0f, const float* __restrict__ h1f,
    const float* __restrict__ outf, float* __restrict__ dst) {
  const int i = blockIdx.x * 256 + threadIdx.x;
  if (i < 131072) dst[i] = h0f[i];
  else if (i < 262144) dst[i] = h1f[i - 131072];
  else if (i < 393216) dst[i] = outf[i - 262144];
}

// ---------------------------------------------------------------------------
extern "C" void kernel_launch(void* const* d_in, const int* in_sizes, int n_in,
                              void* d_out, int out_size, void* d_ws,
                              size_t ws_size, hipStream_t stream) {
  (void)in_sizes; (void)n_in; (void)out_size; (void)ws_size;
  const int* word_ids = (const int*)d_in[0];
  const int* field_ids = (const int*)d_in[1];
  const float* hidden = (const float*)d_in[3];
  const float* context = (const float*)d_in[4];
  const float* prev_output = (const float*)d_in[6];
  const float* wtab = (const float*)d_in[7];
  const float* ftab = (const float*)d_in[8];
  const float* W0ih = (const float*)d_in[9];
  const float* W0hh = (const float*)d_in[10];
  const float* b0ih = (const float*)d_in[11];
  const float* b0hh = (const float*)d_in[12];
  const float* W1ih = (const float*)d_in[13];
  const float* W1hh = (const float*)d_in[14];
  const float* b1ih = (const float*)d_in[15];
  const float* b1hh = (const float*)d_in[16];
  const float* Wa = (const float*)d_in[17];
  const float* Wc = (const float*)d_in[18];
  const float* Ww = (const float*)d_in[19];
  const float* bw = (const float*)d_in[20];
  const float* Wf = (const float*)d_in[21];
  const float* bfb = (const float*)d_in[22];

  char* p = (char*)d_ws;
  auto take = [&](size_t bytes) {
    char* r = p;
    p += (bytes + 255) & ~(size_t)255;
    return r;
  };
  u16* W0ih_b = (u16*)take(3072ull * 1600 * 2);
  u16* W0ihO3 = (u16*)take(3072ull * 3072 * 2);
  u16* W0hh3 = (u16*)take(3072ull * 3072 * 2);
  u16* W1ih3 = (u16*)take(3072ull * 3072 * 2);
  u16* W1hh3 = (u16*)take(3072ull * 3072 * 2);
  u16* WaT3 = (u16*)take(1024ull * 3072 * 2);
  u16* Wc3 = (u16*)take(1024ull * 6144 * 2);
  u16* Ww_b = (u16*)take(32000ull * 1024 * 2);
  u16* Wf_b = (u16*)take(512ull * 1024 * 2);
  u16* ctx3 = (u16*)take(8192ull * 3072 * 2);
  float* ctxWa_f = (float*)take(8192ull * 1024 * 4);
  u16* Xwf_b = (u16*)take(4096ull * 576 * 2);
  u16* gi0_all_b = (u16*)take(4096ull * 3072 * 2);
  u16* outall_b = (u16*)take(32ull * 128 * 1024 * 2);
  u16* out3 = (u16*)take(128ull * 3072 * 2);
  float* h0f = (float*)take(128ull * 1024 * 4);
  float* h1f = (float*)take(128ull * 1024 * 4);
  float* outf = (float*)take(128ull * 1024 * 4);
  u16* h0a3 = (u16*)take(128ull * 3072 * 2);
  u16* h1a3 = (u16*)take(128ull * 3072 * 2);
  u16* cat3 = (u16*)take(128ull * 6144 * 2);
  float* Ppart = (float*)take(18ull * 128 * 3072 * 4);
  float* G1ip = (float*)take(6ull * 128 * 3072 * 4);
  float* Wcpart = (float*)take(16ull * 128 * 1024 * 4);
  unsigned* bar = (unsigned*)take(256);

  // barrier counter must be 0 at every call (captured memset replays)
  hipMemsetAsync(bar, 0, 256, stream);

  // ---- prologue ---------------------------------------------------------
  cvt_bf16_vec<<<dim3(2048), 256, 0, stream>>>(W0ih, W0ih_b, 4915200 / 4);
  split3_w4<<<dim3(12288, 4), 256, 0, stream>>>(W0ih, W0hh, W1ih, W1hh,
                                                W0ihO3, W0hh3, W1ih3, W1hh3);
  split3<true><<<dim3(8192), 256, 0, stream>>>(Wc, 2048, 0, Wc3, 2048,
                                               2097152);
  split3<false><<<dim3(32768), 256, 0, stream>>>(context, 1024, 0, ctx3, 1024,
                                                 8388608);
  transpose_split3<<<dim3(4096), 256, 0, stream>>>(Wa, WaT3);
  cvt_bf16_vec<<<dim3(2048), 256, 0, stream>>>(Ww, Ww_b, 32768000 / 4);
  cvt_bf16_vec<<<dim3(2048), 256, 0, stream>>>(Wf, Wf_b, 524288 / 4);
  gather_emb<<<dim3(4096), 256, 0, stream>>>(word_ids, field_ids, wtab, ftab,
                                             Xwf_b);
  init_state<<<dim3(512), 256, 0, stream>>>(hidden, prev_output, h0f, h1f,
                                            h0a3, h1a3, out3);

  // gi0_wf[t] = Xwf @ W0ih[:, :576]^T + bih0  (bf16 out, plain)
  {
    GemmB3 a{};
    a.A[0] = Xwf_b; a.B[0] = W0ih_b; a.C[0] = gi0_all_b; a.ldb[0] = 1600;
    gemm_bt<128, 128, 1, true><<<dim3(768, 1), 256, 0, stream>>>(
        a, 576, 3072, 24, 576, b0ih, 0);
  }
  // ctxWa = context @ Wa (split-triple, f32 out)
  {
    GemmB3 a{};
    a.A[0] = ctx3; a.B[0] = WaT3; a.C[0] = ctxWa_f; a.ldb[0] = 3072;
    gemm_bt<128, 128, 0, false><<<dim3(512, 1), 256, 0, stream>>>(
        a, 3072, 1024, 8, 3072, nullptr, 0);
  }
  // seed G0h(0) = h0_init @ W0hh -> Ppart planes 6-11
  {
    GemmP a{};
    a.A[0] = h0a3; a.B[0] = W0hh3; a.C[0] = Ppart + 6ull * 393216;
    gemm_part<128, 64><<<dim3(288, 1), 256, 0, stream>>>(
        a, 3072, 3072, 3072, 48, 6, 8, 128);
  }

  // ---- decode loop: single persistent kernel ----------------------------
  {
    PK a;
    a.out3 = out3; a.h0a3 = h0a3; a.h1a3 = h1a3; a.cat3 = cat3;
    a.outall = outall_b;
    a.h0f = h0f; a.h1f = h1f; a.outf = outf;
    a.gi0 = gi0_all_b;
    a.W0ihO3 = W0ihO3; a.W0hh3 = W0hh3; a.W1hh3 = W1hh3; a.W1ih3 = W1ih3;
    a.Wc3 = Wc3;
    a.ctxWa = ctxWa_f; a.ctxf = context;
    a.bhh0 = b0hh; a.bih1 = b1ih; a.bhh1 = b1hh;
    a.Ppart = Ppart; a.G1ip = G1ip; a.Wcpart = Wcpart;
    a.bar = bar;
    decode_pk<<<dim3(512), 256, 0, stream>>>(a);
  }

  // ---- generator (round-9 exact config: mt-major, cached stores, swz) ---
  {
    GemmB3 a{};
    a.A[0] = outall_b; a.B[0] = Ww_b; a.C[0] = d_out; a.ldb[0] = 1024;
    gemm_bt<128, 128, 0, true><<<dim3(8000, 1), 256, 0, stream>>>(
        a, 1024, 32000, 250, 1024, bw, 1);
  }
  {
    GemmB3 a{};
    a.A[0] = outall_b; a.B[0] = Wf_b;
    a.C[0] = (float*)d_out + 131072000ull; a.ldb[0] = 1024;
    gemm_bt<128, 128, 0, true><<<dim3(128, 1), 256, 0, stream>>>(
        a, 1024, 512, 4, 1024, bfb, 0);
  }
  final_copy<<<dim3(1536), 256, 0, stream>>>(
      h0f, h1f, outf, (float*)d_out + 133169152ull);
}

// Round 13
// 2879.448 us; speedup vs baseline: 6.1556x; 6.1556x over previous
//
#include <hip/hip_runtime.h>

// ---------------------------------------------------------------------------
// RNN attention decoder (GRU x2 + general attention + generator), MI355X.
// Round 13 (base = round-10/11 multi-launch loop, persistent/barrier dead):
//   - generator: TIME-CHUNKED tile order (10 chunks x 25 nt-panels x 32 mt).
//     Working set per chunk (B 6.4MB + A 8MB) fits L3 alongside the write
//     stream -> B read from HBM once per chunk, A re-reads hit L3.
//   - loop: K-split 6->4 on the two 3072-K GEMM launches (partial-plane
//     traffic -33%, still 384 blocks/launch = 1.5/CU).
// Precision (verified round 6): split-bf16 hi/lo 3-term K-concat on all
// recurrence/attention GEMMs; plain bf16 generator.
// ---------------------------------------------------------------------------

using u16 = unsigned short;
typedef __attribute__((ext_vector_type(4))) float f32x4;
typedef __attribute__((ext_vector_type(4))) u16 u16x4;
typedef __attribute__((ext_vector_type(8))) u16 u16x8;
typedef __attribute__((ext_vector_type(8))) __bf16 bf16x8;

#define DEVFN static __device__ __forceinline__

DEVFN u16 f2bf(float f) {
  unsigned u = __float_as_uint(f);
  return (u16)((u + 0x7FFFu + ((u >> 16) & 1u)) >> 16);
}
DEVFN float bf2f(u16 h) { return __uint_as_float(((unsigned)h) << 16); }
DEVFN float sigm(float x) { return 1.0f / (1.0f + expf(-x)); }
DEVFN float gru_gate(float ir, float iz, float inn,
                     float hr, float hz, float hn, float hprev) {
  float r = sigm(ir + hr);
  float z = sigm(iz + hz);
  float n = tanhf(inn + r * hn);
  return (1.0f - z) * n + z * hprev;
}

// ---------------------------------------------------------------------------
// Full-K GEMM C = A * B^T (prologue / generator).
// mode 0: mt-major (mt = bx/Ntiles).  mode 2: chunked 25-nt x 32-mt.
// ---------------------------------------------------------------------------
struct GemmB3 {
  const u16* A[3];
  const u16* B[3];
  void* C[3];
  int ldb[3];
};

template <int BM, int BN, int OUTMODE, bool BIAS>
__global__ __launch_bounds__(256) void gemm_bt(
    GemmB3 args, int lda, int ldc, int Ntiles, int K,
    const float* __restrict__ bias, int mode) {
  constexpr int MF = BM / 32;
  constexpr int NF = BN / 32;
  constexpr int IA = (BM * 8) / 256;
  constexpr int IB = (BN * 8) / 256;
  __shared__ alignas(16) u16 lsA[BM * 64];
  __shared__ alignas(16) u16 lsB[BN * 64];

  const int g = blockIdx.y;
  const int bx = blockIdx.x;
  int mt, nt;
  if (mode == 2) {
    const int c = bx / 800;        // chunk of 25 nt-panels
    const int r = bx - c * 800;
    mt = r & 31;
    nt = c * 25 + (r >> 5);
  } else {
    mt = bx / Ntiles;
    nt = bx - mt * Ntiles;
  }
  const int tid = threadIdx.x;
  const int lane = tid & 63;
  const int wv = tid >> 6;
  const int wr = wv >> 1, wc = wv & 1;
  const int l15 = lane & 15, l4 = lane >> 4;
  const int ldb = args.ldb[g];
  const u16* __restrict__ Ag = args.A[g] + (size_t)mt * BM * lda;
  const u16* __restrict__ Bg = args.B[g] + (size_t)nt * BN * ldb;

  f32x4 acc[MF][NF];
#pragma unroll
  for (int m = 0; m < MF; ++m)
#pragma unroll
    for (int n = 0; n < NF; ++n) acc[m][n] = f32x4{0.f, 0.f, 0.f, 0.f};

  const int KT = K >> 6;
  for (int kt = 0; kt < KT; ++kt) {
#pragma unroll
    for (int i = 0; i < IA; ++i) {
      const int chunk = i * 256 + tid;
      const int row = chunk >> 3, c8 = chunk & 7;
      const int cs = c8 ^ (row & 7);
      u16x8 v = *reinterpret_cast<const u16x8*>(
          Ag + (size_t)row * lda + (kt * 64 + c8 * 8));
      *reinterpret_cast<u16x8*>(lsA + row * 64 + cs * 8) = v;
    }
#pragma unroll
    for (int i = 0; i < IB; ++i) {
      const int chunk = i * 256 + tid;
      const int row = chunk >> 3, c8 = chunk & 7;
      const int cs = c8 ^ (row & 7);
      u16x8 v = *reinterpret_cast<const u16x8*>(
          Bg + (size_t)row * ldb + (kt * 64 + c8 * 8));
      *reinterpret_cast<u16x8*>(lsB + row * 64 + cs * 8) = v;
    }
    __syncthreads();
#pragma unroll
    for (int ks = 0; ks < 2; ++ks) {
      bf16x8 av[MF], bv[NF];
#pragma unroll
      for (int m = 0; m < MF; ++m) {
        const int row = wr * (BM / 2) + m * 16 + l15;
        const int cc = (ks * 4 + l4) ^ (row & 7);
        av[m] = *reinterpret_cast<const bf16x8*>(lsA + row * 64 + cc * 8);
      }
#pragma unroll
      for (int n = 0; n < NF; ++n) {
        const int row = wc * (BN / 2) + n * 16 + l15;
        const int cc = (ks * 4 + l4) ^ (row & 7);
        bv[n] = *reinterpret_cast<const bf16x8*>(lsB + row * 64 + cc * 8);
      }
#pragma unroll
      for (int m = 0; m < MF; ++m)
#pragma unroll
        for (int n = 0; n < NF; ++n)
          acc[m][n] = __builtin_amdgcn_mfma_f32_16x16x32_bf16(
              av[m], bv[n], acc[m][n], 0, 0, 0);
    }
    __syncthreads();
  }

#pragma unroll
  for (int m = 0; m < MF; ++m) {
    const int grow = mt * BM + wr * (BM / 2) + m * 16 + l4 * 4;
#pragma unroll
    for (int n = 0; n < NF; ++n) {
      const int gcol = nt * BN + wc * (BN / 2) + n * 16 + l15;
      const float bsv = BIAS ? bias[gcol] : 0.f;
#pragma unroll
      for (int j = 0; j < 4; ++j) {
        const float v = acc[m][n][j] + bsv;
        const size_t idx = (size_t)(grow + j) * ldc + gcol;
        if constexpr (OUTMODE == 0) {
          ((float*)args.C[g])[idx] = v;
        } else {
          ((u16*)args.C[g])[idx] = f2bf(v);
        }
      }
    }
  }
}

// ---------------------------------------------------------------------------
// K-split partial GEMM: C[g][plane=ks] = A * B^T over K-slice ks.
// ---------------------------------------------------------------------------
struct GemmP {
  const u16* A[3];
  const u16* B[3];
  float* C[3];
};

template <int BM, int BN>
__global__ __launch_bounds__(256) void gemm_part(
    GemmP args, int lda, int ldb, int N, int Ntiles, int KS, int nkt,
    int Mrows) {
  constexpr int MF = BM / 32;
  constexpr int NF = BN / 32;
  constexpr int IA = (BM * 8) / 256;
  constexpr int IB = (BN * 8) / 256;
  __shared__ alignas(16) u16 lsA[BM * 64];
  __shared__ alignas(16) u16 lsB[BN * 64];

  const int g = blockIdx.y;
  const int bx = blockIdx.x;
  const int tile = bx / KS;
  const int ks = bx - tile * KS;
  const int mt = tile / Ntiles;
  const int nt = tile - mt * Ntiles;
  const int tid = threadIdx.x;
  const int lane = tid & 63;
  const int wv = tid >> 6;
  const int wr = wv >> 1, wc = wv & 1;
  const int l15 = lane & 15, l4 = lane >> 4;
  const u16* __restrict__ Ag = args.A[g] + (size_t)mt * BM * lda;
  const u16* __restrict__ Bg = args.B[g] + (size_t)nt * BN * ldb;
  float* __restrict__ Cg =
      args.C[g] + (size_t)ks * Mrows * N + (size_t)mt * BM * N;

  f32x4 acc[MF][NF];
#pragma unroll
  for (int m = 0; m < MF; ++m)
#pragma unroll
    for (int n = 0; n < NF; ++n) acc[m][n] = f32x4{0.f, 0.f, 0.f, 0.f};

  const int kt0 = ks * nkt;
  for (int kk = 0; kk < nkt; ++kk) {
    const int kt = kt0 + kk;
#pragma unroll
    for (int i = 0; i < IA; ++i) {
      const int chunk = i * 256 + tid;
      const int row = chunk >> 3, c8 = chunk & 7;
      const int cs = c8 ^ (row & 7);
      u16x8 v = *reinterpret_cast<const u16x8*>(
          Ag + (size_t)row * lda + (kt * 64 + c8 * 8));
      *reinterpret_cast<u16x8*>(lsA + row * 64 + cs * 8) = v;
    }
#pragma unroll
    for (int i = 0; i < IB; ++i) {
      const int chunk = i * 256 + tid;
      const int row = chunk >> 3, c8 = chunk & 7;
      const int cs = c8 ^ (row & 7);
      u16x8 v = *reinterpret_cast<const u16x8*>(
          Bg + (size_t)row * ldb + (kt * 64 + c8 * 8));
      *reinterpret_cast<u16x8*>(lsB + row * 64 + cs * 8) = v;
    }
    __syncthreads();
#pragma unroll
    for (int k2 = 0; k2 < 2; ++k2) {
      bf16x8 av[MF], bv[NF];
#pragma unroll
      for (int m = 0; m < MF; ++m) {
        const int row = wr * (BM / 2) + m * 16 + l15;
        const int cc = (k2 * 4 + l4) ^ (row & 7);
        av[m] = *reinterpret_cast<const bf16x8*>(lsA + row * 64 + cc * 8);
      }
#pragma unroll
      for (int n = 0; n < NF; ++n) {
        const int row = wc * (BN / 2) + n * 16 + l15;
        const int cc = (k2 * 4 + l4) ^ (row & 7);
        bv[n] = *reinterpret_cast<const bf16x8*>(lsB + row * 64 + cc * 8);
      }
#pragma unroll
      for (int m = 0; m < MF; ++m)
#pragma unroll
        for (int n = 0; n < NF; ++n)
          acc[m][n] = __builtin_amdgcn_mfma_f32_16x16x32_bf16(
              av[m], bv[n], acc[m][n], 0, 0, 0);
    }
    __syncthreads();
  }

#pragma unroll
  for (int m = 0; m < MF; ++m) {
    const int row = wr * (BM / 2) + m * 16 + l4 * 4;
#pragma unroll
    for (int n = 0; n < NF; ++n) {
      const int col = nt * BN + wc * (BN / 2) + n * 16 + l15;
#pragma unroll
      for (int j = 0; j < 4; ++j)
        Cg[(size_t)(row + j) * N + col] = acc[m][n][j];
    }
  }
}

// ---------------------------------------------------------------------------
// prologue helpers
// ---------------------------------------------------------------------------
__global__ __launch_bounds__(256) void cvt_bf16_vec(
    const float* __restrict__ in, u16* __restrict__ out, int n4) {
  int i = blockIdx.x * 256 + threadIdx.x;
  const int stride = gridDim.x * 256;
  for (; i < n4; i += stride) {
    f32x4 v = ((const f32x4*)in)[i];
    u16x4 o;
    o[0] = f2bf(v[0]); o[1] = f2bf(v[1]); o[2] = f2bf(v[2]); o[3] = f2bf(v[3]);
    ((u16x4*)out)[i] = o;
  }
}

__global__ __launch_bounds__(256) void split3_w4(
    const float* __restrict__ W0ih, const float* __restrict__ W0hh,
    const float* __restrict__ W1ih, const float* __restrict__ W1hh,
    u16* __restrict__ W0ihO3, u16* __restrict__ W0hh3,
    u16* __restrict__ W1ih3, u16* __restrict__ W1hh3) {
  const int g = blockIdx.y;
  const int idx = blockIdx.x * 256 + threadIdx.x;  // 3145728
  const int r = idx >> 10, c = idx & 1023;
  const float* src;
  int ld, ofs;
  u16* dst;
  if (g == 0) { src = W0ih; ld = 1600; ofs = 576; dst = W0ihO3; }
  else if (g == 1) { src = W0hh; ld = 1024; ofs = 0; dst = W0hh3; }
  else if (g == 2) { src = W1ih; ld = 1024; ofs = 0; dst = W1ih3; }
  else { src = W1hh; ld = 1024; ofs = 0; dst = W1hh3; }
  const float x = src[(size_t)r * ld + ofs + c];
  const u16 hi = f2bf(x);
  const u16 lo = f2bf(x - bf2f(hi));
  u16* d = dst + (size_t)r * 3072;
  d[c] = hi;
  d[1024 + c] = hi;
  d[2048 + c] = lo;
}

template <bool BSIDE>
__global__ __launch_bounds__(256) void split3(
    const float* __restrict__ src, int src_ld, int src_ofs,
    u16* __restrict__ dst, int C, int total) {
  const int idx = blockIdx.x * 256 + threadIdx.x;
  if (idx >= total) return;
  const int r = idx / C, c = idx - r * C;
  const float x = src[(size_t)r * src_ld + src_ofs + c];
  const u16 hi = f2bf(x);
  const u16 lo = f2bf(x - bf2f(hi));
  u16* d = dst + (size_t)r * (3 * C);
  d[c] = hi;
  d[C + c] = BSIDE ? hi : lo;
  d[2 * C + c] = BSIDE ? lo : hi;
}

__global__ __launch_bounds__(256) void transpose_split3(
    const float* __restrict__ Wa, u16* __restrict__ dst) {
  const int idx = blockIdx.x * 256 + threadIdx.x;
  const int i = idx >> 10, j = idx & 1023;
  const float x = Wa[idx];
  const u16 hi = f2bf(x);
  const u16 lo = f2bf(x - bf2f(hi));
  u16* d = dst + (size_t)j * 3072;
  d[i] = hi;
  d[1024 + i] = hi;
  d[2048 + i] = lo;
}

__global__ __launch_bounds__(256) void gather_emb(
    const int* __restrict__ wid, const int* __restrict__ fid,
    const float* __restrict__ wtab, const float* __restrict__ ftab,
    u16* __restrict__ Xwf) {
  const int r = blockIdx.x;
  const int w = wid[r], f = fid[r];
  u16* dst = Xwf + (size_t)r * 576;
  const float* wsrc = wtab + (size_t)w * 512;
  const float* fsrc = ftab + (size_t)f * 64;
  for (int c = threadIdx.x; c < 512; c += 256) dst[c] = f2bf(wsrc[c]);
  if (threadIdx.x < 64) dst[512 + threadIdx.x] = f2bf(fsrc[threadIdx.x]);
}

DEVFN void trip_store(u16* base3, int c, float x) {
  const u16 hi = f2bf(x);
  const u16 lo = f2bf(x - bf2f(hi));
  base3[c] = hi;
  base3[1024 + c] = lo;
  base3[2048 + c] = hi;
}

__global__ __launch_bounds__(256) void init_state(
    const float* __restrict__ hidden, const float* __restrict__ prev_out,
    float* __restrict__ h0f, float* __restrict__ h1f,
    u16* __restrict__ h0a3, u16* __restrict__ h1a3, u16* __restrict__ out3) {
  const int i = blockIdx.x * 256 + threadIdx.x;
  const int b = i >> 10, c = i & 1023;
  const float aa = hidden[i], bb = hidden[131072 + i], po = prev_out[i];
  h0f[i] = aa;
  h1f[i] = bb;
  trip_store(h0a3 + (size_t)b * 3072, c, aa);
  trip_store(h1a3 + (size_t)b * 3072, c, bb);
  trip_store(out3 + (size_t)b * 3072, c, po);
}

// ---------------------------------------------------------------------------
// per-step kernels.  Ppart planes: 0-3 P, 4-7 G0h, 8-11 G1h.  G1ip: 0-3.
// ---------------------------------------------------------------------------
__global__ __launch_bounds__(256) void gate0_red(
    const float* __restrict__ Ppart, const u16* __restrict__ gi0_t,
    const float* __restrict__ bhh0, float* __restrict__ h0f,
    u16* __restrict__ h0a3) {
  const int i = blockIdx.x * 256 + threadIdx.x;  // 131072
  const int b = i >> 10, c = i & 1023;
  const size_t r3 = (size_t)b * 3072;
  float pr = 0.f, pz = 0.f, pn = 0.f, qr = 0.f, qz = 0.f, qn = 0.f;
#pragma unroll
  for (int ks = 0; ks < 4; ++ks) {
    const float* P0 = Ppart + (size_t)ks * 393216 + r3;
    const float* P1 = Ppart + (size_t)(4 + ks) * 393216 + r3;
    pr += P0[c]; pz += P0[1024 + c]; pn += P0[2048 + c];
    qr += P1[c]; qz += P1[1024 + c]; qn += P1[2048 + c];
  }
  const u16* gi = gi0_t + r3;
  const float h0 = gru_gate(bf2f(gi[c]) + pr, bf2f(gi[1024 + c]) + pz,
                            bf2f(gi[2048 + c]) + pn, qr + bhh0[c],
                            qz + bhh0[1024 + c], qn + bhh0[2048 + c], h0f[i]);
  h0f[i] = h0;
  const u16 hb = f2bf(h0);
  const u16 lb = f2bf(h0 - bf2f(hb));
  h0a3[r3 + c] = hb;
  h0a3[r3 + 1024 + c] = lb;
  h0a3[r3 + 2048 + c] = hb;
}

__global__ __launch_bounds__(256) void attn_red(
    const float* __restrict__ G1ip, const float* __restrict__ Ppart,
    const float* __restrict__ bih1, const float* __restrict__ bhh1,
    const float* __restrict__ ctxWa, const float* __restrict__ ctxf,
    float* __restrict__ h1f, u16* __restrict__ h1a3, u16* __restrict__ cat3) {
  __shared__ float sh1[1024];
  __shared__ float red[256];
  __shared__ float ssc[64];
  const int b = blockIdx.x;
  const int tid = threadIdx.x;
  const int k = tid * 4;
  const size_t r3 = (size_t)b * 3072;
  const size_t r1 = (size_t)b * 1024;
  u16* catr = cat3 + (size_t)b * 6144;

  {
    f32x4 ir = {0.f, 0.f, 0.f, 0.f}, iz = ir, in_ = ir;
    f32x4 hr = ir, hz = ir, hn = ir;
#pragma unroll
    for (int ks = 0; ks < 4; ++ks) {
      const float* gi = G1ip + (size_t)ks * 393216 + r3;
      const float* gh = Ppart + (size_t)(8 + ks) * 393216 + r3;
      ir += *(const f32x4*)(gi + k);
      iz += *(const f32x4*)(gi + 1024 + k);
      in_ += *(const f32x4*)(gi + 2048 + k);
      hr += *(const f32x4*)(gh + k);
      hz += *(const f32x4*)(gh + 1024 + k);
      hn += *(const f32x4*)(gh + 2048 + k);
    }
    f32x4 bir = *(const f32x4*)(bih1 + k);
    f32x4 biz = *(const f32x4*)(bih1 + 1024 + k);
    f32x4 bin_ = *(const f32x4*)(bih1 + 2048 + k);
    f32x4 bhr = *(const f32x4*)(bhh1 + k);
    f32x4 bhz = *(const f32x4*)(bhh1 + 1024 + k);
    f32x4 bhn = *(const f32x4*)(bhh1 + 2048 + k);
    f32x4 hp = *(const f32x4*)(h1f + r1 + k);
    f32x4 hnew;
    u16x4 hb, lb;
#pragma unroll
    for (int j = 0; j < 4; ++j) {
      hnew[j] = gru_gate(ir[j] + bir[j], iz[j] + biz[j], in_[j] + bin_[j],
                         hr[j] + bhr[j], hz[j] + bhz[j], hn[j] + bhn[j], hp[j]);
      sh1[k + j] = hnew[j];
      hb[j] = f2bf(hnew[j]);
      lb[j] = f2bf(hnew[j] - bf2f(hb[j]));
    }
    *(f32x4*)(h1f + r1 + k) = hnew;
    *(u16x4*)(h1a3 + r3 + k) = hb;
    *(u16x4*)(h1a3 + r3 + 1024 + k) = lb;
    *(u16x4*)(h1a3 + r3 + 2048 + k) = hb;
    *(u16x4*)(catr + 1024 + k) = hb;
    *(u16x4*)(catr + 2048 + 1024 + k) = lb;
    *(u16x4*)(catr + 4096 + 1024 + k) = hb;
  }
  __syncthreads();

  const int s = tid >> 2, part = tid & 3;
  {
    const float* cw = ctxWa + ((size_t)b * 64 + s) * 1024 + part * 256;
    const float* hh = sh1 + part * 256;
    float p = 0.f;
    for (int i = 0; i < 256; i += 4) {
      f32x4 v = *(const f32x4*)(cw + i);
      p += v[0] * hh[i] + v[1] * hh[i + 1] + v[2] * hh[i + 2] +
           v[3] * hh[i + 3];
    }
    red[tid] = p;
  }
  __syncthreads();
  if (part == 0) ssc[s] = red[tid] + red[tid + 1] + red[tid + 2] + red[tid + 3];
  __syncthreads();
  if (tid == 0) {
    float mx = -1e30f;
    for (int i = 0; i < 64; ++i) mx = fmaxf(mx, ssc[i]);
    float sm = 0.f;
    for (int i = 0; i < 64; ++i) {
      float e = expf(ssc[i] - mx);
      ssc[i] = e;
      sm += e;
    }
    const float inv = 1.0f / sm;
    for (int i = 0; i < 64; ++i) ssc[i] *= inv;
  }
  __syncthreads();
  {
    float a0 = 0.f, a1 = 0.f, a2 = 0.f, a3 = 0.f;
    const float* cb = ctxf + (size_t)b * 65536 + k;
    for (int s2 = 0; s2 < 64; ++s2) {
      const float w = ssc[s2];
      f32x4 v = *(const f32x4*)(cb + (size_t)s2 * 1024);
      a0 += w * v[0]; a1 += w * v[1]; a2 += w * v[2]; a3 += w * v[3];
    }
    f32x4 cv{a0, a1, a2, a3};
    u16x4 ch, cl;
#pragma unroll
    for (int j = 0; j < 4; ++j) {
      ch[j] = f2bf(cv[j]);
      cl[j] = f2bf(cv[j] - bf2f(ch[j]));
    }
    *(u16x4*)(catr + k) = ch;
    *(u16x4*)(catr + 2048 + k) = cl;
    *(u16x4*)(catr + 4096 + k) = ch;
  }
}

__global__ __launch_bounds__(256) void out_red(
    const float* __restrict__ Wcpart, float* __restrict__ outf,
    u16* __restrict__ outall_t, u16* __restrict__ out3) {
  const int i = blockIdx.x * 256 + threadIdx.x;  // 131072
  const int b = i >> 10, c = i & 1023;
  float v = 0.f;
#pragma unroll
  for (int ks = 0; ks < 16; ++ks) v += Wcpart[(size_t)ks * 131072 + i];
  const float o = tanhf(v);
  outf[i] = o;
  outall_t[i] = f2bf(o);
  const u16 hb = f2bf(o);
  const u16 lb = f2bf(o - bf2f(hb));
  u16* d = out3 + (size_t)b * 3072;
  d[c] = hb;
  d[1024 + c] = lb;
  d[2048 + c] = hb;
}

__global__ __launch_bounds__(256) void final_copy(
    const float* __restrict__ h0f, const float* __restrict__ h1f,
    const float* __restrict__ outf, float* __restrict__ dst) {
  const int i = blockIdx.x * 256 + threadIdx.x;
  if (i < 131072) dst[i] = h0f[i];
  else if (i < 262144) dst[i] = h1f[i - 131072];
  else if (i < 393216) dst[i] = outf[i - 262144];
}

// ---------------------------------------------------------------------------
extern "C" void kernel_launch(void* const* d_in, const int* in_sizes, int n_in,
                              void* d_out, int out_size, void* d_ws,
                              size_t ws_size, hipStream_t stream) {
  (void)in_sizes; (void)n_in; (void)out_size; (void)ws_size;
  const int* word_ids = (const int*)d_in[0];
  const int* field_ids = (const int*)d_in[1];
  const float* hidden = (const float*)d_in[3];
  const float* context = (const float*)d_in[4];
  const float* prev_output = (const float*)d_in[6];
  const float* wtab = (const float*)d_in[7];
  const float* ftab = (const float*)d_in[8];
  const float* W0ih = (const float*)d_in[9];
  const float* W0hh = (const float*)d_in[10];
  const float* b0ih = (const float*)d_in[11];
  const float* b0hh = (const float*)d_in[12];
  const float* W1ih = (const float*)d_in[13];
  const float* W1hh = (const float*)d_in[14];
  const float* b1ih = (const float*)d_in[15];
  const float* b1hh = (const float*)d_in[16];
  const float* Wa = (const float*)d_in[17];
  const float* Wc = (const float*)d_in[18];
  const float* Ww = (const float*)d_in[19];
  const float* bw = (const float*)d_in[20];
  const float* Wf = (const float*)d_in[21];
  const float* bfb = (const float*)d_in[22];

  char* p = (char*)d_ws;
  auto take = [&](size_t bytes) {
    char* r = p;
    p += (bytes + 255) & ~(size_t)255;
    return r;
  };
  u16* W0ih_b = (u16*)take(3072ull * 1600 * 2);
  u16* W0ihO3 = (u16*)take(3072ull * 3072 * 2);
  u16* W0hh3 = (u16*)take(3072ull * 3072 * 2);
  u16* W1ih3 = (u16*)take(3072ull * 3072 * 2);
  u16* W1hh3 = (u16*)take(3072ull * 3072 * 2);
  u16* WaT3 = (u16*)take(1024ull * 3072 * 2);
  u16* Wc3 = (u16*)take(1024ull * 6144 * 2);
  u16* Ww_b = (u16*)take(32000ull * 1024 * 2);
  u16* Wf_b = (u16*)take(512ull * 1024 * 2);
  u16* ctx3 = (u16*)take(8192ull * 3072 * 2);
  float* ctxWa_f = (float*)take(8192ull * 1024 * 4);
  u16* Xwf_b = (u16*)take(4096ull * 576 * 2);
  u16* gi0_all_b = (u16*)take(4096ull * 3072 * 2);
  u16* outall_b = (u16*)take(32ull * 128 * 1024 * 2);
  u16* out3 = (u16*)take(128ull * 3072 * 2);
  float* h0f = (float*)take(128ull * 1024 * 4);
  float* h1f = (float*)take(128ull * 1024 * 4);
  float* outf = (float*)take(128ull * 1024 * 4);
  u16* h0a3 = (u16*)take(128ull * 3072 * 2);
  u16* h1a3 = (u16*)take(128ull * 3072 * 2);
  u16* cat3 = (u16*)take(128ull * 6144 * 2);
  float* Ppart = (float*)take(12ull * 128 * 3072 * 4);   // 0-3 P, 4-7 G0h, 8-11 G1h
  float* G1ip = (float*)take(4ull * 128 * 3072 * 4);     // planes 0-3
  float* Wcpart = (float*)take(16ull * 128 * 1024 * 4);  // planes 0-15

  // ---- prologue ---------------------------------------------------------
  cvt_bf16_vec<<<dim3(2048), 256, 0, stream>>>(W0ih, W0ih_b, 4915200 / 4);
  split3_w4<<<dim3(12288, 4), 256, 0, stream>>>(W0ih, W0hh, W1ih, W1hh,
                                                W0ihO3, W0hh3, W1ih3, W1hh3);
  split3<true><<<dim3(8192), 256, 0, stream>>>(Wc, 2048, 0, Wc3, 2048,
                                               2097152);
  split3<false><<<dim3(32768), 256, 0, stream>>>(context, 1024, 0, ctx3, 1024,
                                                 8388608);
  transpose_split3<<<dim3(4096), 256, 0, stream>>>(Wa, WaT3);
  cvt_bf16_vec<<<dim3(2048), 256, 0, stream>>>(Ww, Ww_b, 32768000 / 4);
  cvt_bf16_vec<<<dim3(2048), 256, 0, stream>>>(Wf, Wf_b, 524288 / 4);
  gather_emb<<<dim3(4096), 256, 0, stream>>>(word_ids, field_ids, wtab, ftab,
                                             Xwf_b);
  init_state<<<dim3(512), 256, 0, stream>>>(hidden, prev_output, h0f, h1f,
                                            h0a3, h1a3, out3);

  // gi0_wf[t] = Xwf @ W0ih[:, :576]^T + bih0  (bf16 out, plain)
  {
    GemmB3 a{};
    a.A[0] = Xwf_b; a.B[0] = W0ih_b; a.C[0] = gi0_all_b; a.ldb[0] = 1600;
    gemm_bt<128, 128, 1, true><<<dim3(768, 1), 256, 0, stream>>>(
        a, 576, 3072, 24, 576, b0ih, 0);
  }
  // ctxWa = context @ Wa (split-triple, f32 out)
  {
    GemmB3 a{};
    a.A[0] = ctx3; a.B[0] = WaT3; a.C[0] = ctxWa_f; a.ldb[0] = 3072;
    gemm_bt<128, 128, 0, false><<<dim3(512, 1), 256, 0, stream>>>(
        a, 3072, 1024, 8, 3072, nullptr, 0);
  }
  // seed G0h(0) = h0_init @ W0hh -> Ppart planes 4-7
  {
    GemmP a{};
    a.A[0] = h0a3; a.B[0] = W0hh3; a.C[0] = Ppart + 4ull * 393216;
    gemm_part<128, 64><<<dim3(192, 1), 256, 0, stream>>>(
        a, 3072, 3072, 3072, 48, 4, 12, 128);
  }

  // ---- decode loop: 6 launches/step, KS=4 on 3072-K GEMMs ---------------
  for (int t = 0; t < 32; ++t) {
    {
      // GEMM1: {P(t) -> planes 0-3, G1h(t) -> planes 8-11}
      GemmP a{};
      a.A[0] = out3;  a.B[0] = W0ihO3; a.C[0] = Ppart;
      a.A[1] = h1a3;  a.B[1] = W1hh3;  a.C[1] = Ppart + 8ull * 393216;
      gemm_part<128, 64><<<dim3(192, 2), 256, 0, stream>>>(
          a, 3072, 3072, 3072, 48, 4, 12, 128);
    }
    gate0_red<<<dim3(512), 256, 0, stream>>>(
        Ppart, gi0_all_b + (size_t)t * 393216, b0hh, h0f, h0a3);
    {
      // GEMM2: {G1i(t) -> G1ip, G0h(t+1) -> Ppart planes 4-7}
      GemmP a{};
      a.A[0] = h0a3; a.B[0] = W1ih3; a.C[0] = G1ip;
      a.A[1] = h0a3; a.B[1] = W0hh3; a.C[1] = Ppart + 4ull * 393216;
      gemm_part<128, 64><<<dim3(192, 2), 256, 0, stream>>>(
          a, 3072, 3072, 3072, 48, 4, 12, 128);
    }
    attn_red<<<dim3(128), 256, 0, stream>>>(G1ip, Ppart, b1ih, b1hh, ctxWa_f,
                                            context, h1f, h1a3, cat3);
    {
      // GEMM3: Wc(t), tiles 2x16, Ksplit16, K=6144
      GemmP a{};
      a.A[0] = cat3; a.B[0] = Wc3; a.C[0] = Wcpart;
      gemm_part<64, 64><<<dim3(512, 1), 256, 0, stream>>>(
          a, 6144, 6144, 1024, 16, 16, 6, 128);
    }
    out_red<<<dim3(512), 256, 0, stream>>>(
        Wcpart, outf, outall_b + (size_t)t * 131072, out3);
  }

  // ---- generator (time-chunked tile order) ------------------------------
  {
    GemmB3 a{};
    a.A[0] = outall_b; a.B[0] = Ww_b; a.C[0] = d_out; a.ldb[0] = 1024;
    gemm_bt<128, 128, 0, true><<<dim3(8000, 1), 256, 0, stream>>>(
        a, 1024, 32000, 250, 1024, bw, 2);
  }
  {
    GemmB3 a{};
    a.A[0] = outall_b; a.B[0] = Wf_b;
    a.C[0] = (float*)d_out + 131072000ull; a.ldb[0] = 1024;
    gemm_bt<128, 128, 0, true><<<dim3(128, 1), 256, 0, stream>>>(
        a, 1024, 512, 4, 1024, bfb, 0);
  }
  final_copy<<<dim3(1536), 256, 0, stream>>>(
      h0f, h1f, outf, (float*)d_out + 133169152ull);
}

// Round 14
// 2842.451 us; speedup vs baseline: 6.2357x; 1.0130x over previous
//
#include <hip/hip_runtime.h>

// ---------------------------------------------------------------------------
// RNN attention decoder (GRU x2 + general attention + generator), MI355X.
// Round 14 (base = round 13):
//   - GEMM staging switched to global_load_lds width-16 (async DMA, no VGPR
//     round-trip): linear LDS dest + pre-swizzled per-lane SOURCE column.
//     Produces the identical LDS[row,x] = global[row, x^(row&7)] mapping as
//     the old reg-staged path -> bit-identical results.
//     (learn_hip m151: 646 -> 874 TF at 128^2 from this one change.)
//   - generator keeps time-chunked tile order (FETCH 890->322 MB, r13).
// Precision (verified round 6): split-bf16 hi/lo 3-term K-concat on all
// recurrence/attention GEMMs; plain bf16 generator.
// ---------------------------------------------------------------------------

using u16 = unsigned short;
typedef __attribute__((ext_vector_type(4))) float f32x4;
typedef __attribute__((ext_vector_type(4))) u16 u16x4;
typedef __attribute__((ext_vector_type(8))) u16 u16x8;
typedef __attribute__((ext_vector_type(8))) __bf16 bf16x8;

#define DEVFN static __device__ __forceinline__

DEVFN u16 f2bf(float f) {
  unsigned u = __float_as_uint(f);
  return (u16)((u + 0x7FFFu + ((u >> 16) & 1u)) >> 16);
}
DEVFN float bf2f(u16 h) { return __uint_as_float(((unsigned)h) << 16); }
DEVFN float sigm(float x) { return 1.0f / (1.0f + expf(-x)); }
DEVFN float gru_gate(float ir, float iz, float inn,
                     float hr, float hz, float hn, float hprev) {
  float r = sigm(ir + hr);
  float z = sigm(iz + hz);
  float n = tanhf(inn + r * hn);
  return (1.0f - z) * n + z * hprev;
}

// async global->LDS stage of one [ROWS][64] bf16 tile with XOR-swizzle.
// LDS layout: LDS[row*64 + x*8] = global[row, (x^(row&7))*8 ..+8)
template <int ROWS>
DEVFN void stage_tile(const u16* __restrict__ G, int ldg, int kt, u16* lds,
                      int tid) {
  constexpr int IT = (ROWS * 8) / 256;  // 16B chunks per thread
  const int wvbase = tid & ~63;
#pragma unroll
  for (int i = 0; i < IT; ++i) {
    const int chunk = i * 256 + tid;
    const int row = chunk >> 3, c8 = chunk & 7;
    const int cs = c8 ^ (row & 7);
    const u16* src = G + (size_t)row * ldg + (kt * 64 + cs * 8);
    u16* dst = lds + (size_t)(i * 256 + wvbase) * 8;  // wave-uniform base
    __builtin_amdgcn_global_load_lds(
        (const __attribute__((address_space(1))) void*)src,
        (__attribute__((address_space(3))) void*)dst, 16, 0, 0);
  }
}

// ---------------------------------------------------------------------------
// Full-K GEMM C = A * B^T (prologue / generator).
// mode 0: mt-major (mt = bx/Ntiles).  mode 2: chunked 25-nt x 32-mt.
// ---------------------------------------------------------------------------
struct GemmB3 {
  const u16* A[3];
  const u16* B[3];
  void* C[3];
  int ldb[3];
};

template <int BM, int BN, int OUTMODE, bool BIAS>
__global__ __launch_bounds__(256) void gemm_bt(
    GemmB3 args, int lda, int ldc, int Ntiles, int K,
    const float* __restrict__ bias, int mode) {
  constexpr int MF = BM / 32;
  constexpr int NF = BN / 32;
  __shared__ alignas(16) u16 lsA[BM * 64];
  __shared__ alignas(16) u16 lsB[BN * 64];

  const int g = blockIdx.y;
  const int bx = blockIdx.x;
  int mt, nt;
  if (mode == 2) {
    const int c = bx / 800;  // chunk of 25 nt-panels
    const int r = bx - c * 800;
    mt = r & 31;
    nt = c * 25 + (r >> 5);
  } else {
    mt = bx / Ntiles;
    nt = bx - mt * Ntiles;
  }
  const int tid = threadIdx.x;
  const int lane = tid & 63;
  const int wv = tid >> 6;
  const int wr = wv >> 1, wc = wv & 1;
  const int l15 = lane & 15, l4 = lane >> 4;
  const int ldb = args.ldb[g];
  const u16* __restrict__ Ag = args.A[g] + (size_t)mt * BM * lda;
  const u16* __restrict__ Bg = args.B[g] + (size_t)nt * BN * ldb;

  f32x4 acc[MF][NF];
#pragma unroll
  for (int m = 0; m < MF; ++m)
#pragma unroll
    for (int n = 0; n < NF; ++n) acc[m][n] = f32x4{0.f, 0.f, 0.f, 0.f};

  const int KT = K >> 6;
  for (int kt = 0; kt < KT; ++kt) {
    stage_tile<BM>(Ag, lda, kt, lsA, tid);
    stage_tile<BN>(Bg, ldb, kt, lsB, tid);
    __syncthreads();
#pragma unroll
    for (int ks = 0; ks < 2; ++ks) {
      bf16x8 av[MF], bv[NF];
#pragma unroll
      for (int m = 0; m < MF; ++m) {
        const int row = wr * (BM / 2) + m * 16 + l15;
        const int cc = (ks * 4 + l4) ^ (row & 7);
        av[m] = *reinterpret_cast<const bf16x8*>(lsA + row * 64 + cc * 8);
      }
#pragma unroll
      for (int n = 0; n < NF; ++n) {
        const int row = wc * (BN / 2) + n * 16 + l15;
        const int cc = (ks * 4 + l4) ^ (row & 7);
        bv[n] = *reinterpret_cast<const bf16x8*>(lsB + row * 64 + cc * 8);
      }
#pragma unroll
      for (int m = 0; m < MF; ++m)
#pragma unroll
        for (int n = 0; n < NF; ++n)
          acc[m][n] = __builtin_amdgcn_mfma_f32_16x16x32_bf16(
              av[m], bv[n], acc[m][n], 0, 0, 0);
    }
    __syncthreads();
  }

#pragma unroll
  for (int m = 0; m < MF; ++m) {
    const int grow = mt * BM + wr * (BM / 2) + m * 16 + l4 * 4;
#pragma unroll
    for (int n = 0; n < NF; ++n) {
      const int gcol = nt * BN + wc * (BN / 2) + n * 16 + l15;
      const float bsv = BIAS ? bias[gcol] : 0.f;
#pragma unroll
      for (int j = 0; j < 4; ++j) {
        const float v = acc[m][n][j] + bsv;
        const size_t idx = (size_t)(grow + j) * ldc + gcol;
        if constexpr (OUTMODE == 0) {
          ((float*)args.C[g])[idx] = v;
        } else {
          ((u16*)args.C[g])[idx] = f2bf(v);
        }
      }
    }
  }
}

// ---------------------------------------------------------------------------
// K-split partial GEMM: C[g][plane=ks] = A * B^T over K-slice ks.
// ---------------------------------------------------------------------------
struct GemmP {
  const u16* A[3];
  const u16* B[3];
  float* C[3];
};

template <int BM, int BN>
__global__ __launch_bounds__(256) void gemm_part(
    GemmP args, int lda, int ldb, int N, int Ntiles, int KS, int nkt,
    int Mrows) {
  constexpr int MF = BM / 32;
  constexpr int NF = BN / 32;
  __shared__ alignas(16) u16 lsA[BM * 64];
  __shared__ alignas(16) u16 lsB[BN * 64];

  const int g = blockIdx.y;
  const int bx = blockIdx.x;
  const int tile = bx / KS;
  const int ks = bx - tile * KS;
  const int mt = tile / Ntiles;
  const int nt = tile - mt * Ntiles;
  const int tid = threadIdx.x;
  const int lane = tid & 63;
  const int wv = tid >> 6;
  const int wr = wv >> 1, wc = wv & 1;
  const int l15 = lane & 15, l4 = lane >> 4;
  const u16* __restrict__ Ag = args.A[g] + (size_t)mt * BM * lda;
  const u16* __restrict__ Bg = args.B[g] + (size_t)nt * BN * ldb;
  float* __restrict__ Cg =
      args.C[g] + (size_t)ks * Mrows * N + (size_t)mt * BM * N;

  f32x4 acc[MF][NF];
#pragma unroll
  for (int m = 0; m < MF; ++m)
#pragma unroll
    for (int n = 0; n < NF; ++n) acc[m][n] = f32x4{0.f, 0.f, 0.f, 0.f};

  const int kt0 = ks * nkt;
  for (int kk = 0; kk < nkt; ++kk) {
    const int kt = kt0 + kk;
    stage_tile<BM>(Ag, lda, kt, lsA, tid);
    stage_tile<BN>(Bg, ldb, kt, lsB, tid);
    __syncthreads();
#pragma unroll
    for (int k2 = 0; k2 < 2; ++k2) {
      bf16x8 av[MF], bv[NF];
#pragma unroll
      for (int m = 0; m < MF; ++m) {
        const int row = wr * (BM / 2) + m * 16 + l15;
        const int cc = (k2 * 4 + l4) ^ (row & 7);
        av[m] = *reinterpret_cast<const bf16x8*>(lsA + row * 64 + cc * 8);
      }
#pragma unroll
      for (int n = 0; n < NF; ++n) {
        const int row = wc * (BN / 2) + n * 16 + l15;
        const int cc = (k2 * 4 + l4) ^ (row & 7);
        bv[n] = *reinterpret_cast<const bf16x8*>(lsB + row * 64 + cc * 8);
      }
#pragma unroll
      for (int m = 0; m < MF; ++m)
#pragma unroll
        for (int n = 0; n < NF; ++n)
          acc[m][n] = __builtin_amdgcn_mfma_f32_16x16x32_bf16(
              av[m], bv[n], acc[m][n], 0, 0, 0);
    }
    __syncthreads();
  }

#pragma unroll
  for (int m = 0; m < MF; ++m) {
    const int row = wr * (BM / 2) + m * 16 + l4 * 4;
#pragma unroll
    for (int n = 0; n < NF; ++n) {
      const int col = nt * BN + wc * (BN / 2) + n * 16 + l15;
#pragma unroll
      for (int j = 0; j < 4; ++j)
        Cg[(size_t)(row + j) * N + col] = acc[m][n][j];
    }
  }
}

// ---------------------------------------------------------------------------
// prologue helpers
// ---------------------------------------------------------------------------
__global__ __launch_bounds__(256) void cvt_bf16_vec(
    const float* __restrict__ in, u16* __restrict__ out, int n4) {
  int i = blockIdx.x * 256 + threadIdx.x;
  const int stride = gridDim.x * 256;
  for (; i < n4; i += stride) {
    f32x4 v = ((const f32x4*)in)[i];
    u16x4 o;
    o[0] = f2bf(v[0]); o[1] = f2bf(v[1]); o[2] = f2bf(v[2]); o[3] = f2bf(v[3]);
    ((u16x4*)out)[i] = o;
  }
}

__global__ __launch_bounds__(256) void split3_w4(
    const float* __restrict__ W0ih, const float* __restrict__ W0hh,
    const float* __restrict__ W1ih, const float* __restrict__ W1hh,
    u16* __restrict__ W0ihO3, u16* __restrict__ W0hh3,
    u16* __restrict__ W1ih3, u16* __restrict__ W1hh3) {
  const int g = blockIdx.y;
  const int idx = blockIdx.x * 256 + threadIdx.x;  // 3145728
  const int r = idx >> 10, c = idx & 1023;
  const float* src;
  int ld, ofs;
  u16* dst;
  if (g == 0) { src = W0ih; ld = 1600; ofs = 576; dst = W0ihO3; }
  else if (g == 1) { src = W0hh; ld = 1024; ofs = 0; dst = W0hh3; }
  else if (g == 2) { src = W1ih; ld = 1024; ofs = 0; dst = W1ih3; }
  else { src = W1hh; ld = 1024; ofs = 0; dst = W1hh3; }
  const float x = src[(size_t)r * ld + ofs + c];
  const u16 hi = f2bf(x);
  const u16 lo = f2bf(x - bf2f(hi));
  u16* d = dst + (size_t)r * 3072;
  d[c] = hi;
  d[1024 + c] = hi;
  d[2048 + c] = lo;
}

template <bool BSIDE>
__global__ __launch_bounds__(256) void split3(
    const float* __restrict__ src, int src_ld, int src_ofs,
    u16* __restrict__ dst, int C, int total) {
  const int idx = blockIdx.x * 256 + threadIdx.x;
  if (idx >= total) return;
  const int r = idx / C, c = idx - r * C;
  const float x = src[(size_t)r * src_ld + src_ofs + c];
  const u16 hi = f2bf(x);
  const u16 lo = f2bf(x - bf2f(hi));
  u16* d = dst + (size_t)r * (3 * C);
  d[c] = hi;
  d[C + c] = BSIDE ? hi : lo;
  d[2 * C + c] = BSIDE ? lo : hi;
}

__global__ __launch_bounds__(256) void transpose_split3(
    const float* __restrict__ Wa, u16* __restrict__ dst) {
  const int idx = blockIdx.x * 256 + threadIdx.x;
  const int i = idx >> 10, j = idx & 1023;
  const float x = Wa[idx];
  const u16 hi = f2bf(x);
  const u16 lo = f2bf(x - bf2f(hi));
  u16* d = dst + (size_t)j * 3072;
  d[i] = hi;
  d[1024 + i] = hi;
  d[2048 + i] = lo;
}

__global__ __launch_bounds__(256) void gather_emb(
    const int* __restrict__ wid, const int* __restrict__ fid,
    const float* __restrict__ wtab, const float* __restrict__ ftab,
    u16* __restrict__ Xwf) {
  const int r = blockIdx.x;
  const int w = wid[r], f = fid[r];
  u16* dst = Xwf + (size_t)r * 576;
  const float* wsrc = wtab + (size_t)w * 512;
  const float* fsrc = ftab + (size_t)f * 64;
  for (int c = threadIdx.x; c < 512; c += 256) dst[c] = f2bf(wsrc[c]);
  if (threadIdx.x < 64) dst[512 + threadIdx.x] = f2bf(fsrc[threadIdx.x]);
}

DEVFN void trip_store(u16* base3, int c, float x) {
  const u16 hi = f2bf(x);
  const u16 lo = f2bf(x - bf2f(hi));
  base3[c] = hi;
  base3[1024 + c] = lo;
  base3[2048 + c] = hi;
}

__global__ __launch_bounds__(256) void init_state(
    const float* __restrict__ hidden, const float* __restrict__ prev_out,
    float* __restrict__ h0f, float* __restrict__ h1f,
    u16* __restrict__ h0a3, u16* __restrict__ h1a3, u16* __restrict__ out3) {
  const int i = blockIdx.x * 256 + threadIdx.x;
  const int b = i >> 10, c = i & 1023;
  const float aa = hidden[i], bb = hidden[131072 + i], po = prev_out[i];
  h0f[i] = aa;
  h1f[i] = bb;
  trip_store(h0a3 + (size_t)b * 3072, c, aa);
  trip_store(h1a3 + (size_t)b * 3072, c, bb);
  trip_store(out3 + (size_t)b * 3072, c, po);
}

// ---------------------------------------------------------------------------
// per-step kernels.  Ppart planes: 0-3 P, 4-7 G0h, 8-11 G1h.  G1ip: 0-3.
// ---------------------------------------------------------------------------
__global__ __launch_bounds__(256) void gate0_red(
    const float* __restrict__ Ppart, const u16* __restrict__ gi0_t,
    const float* __restrict__ bhh0, float* __restrict__ h0f,
    u16* __restrict__ h0a3) {
  const int i = blockIdx.x * 256 + threadIdx.x;  // 131072
  const int b = i >> 10, c = i & 1023;
  const size_t r3 = (size_t)b * 3072;
  float pr = 0.f, pz = 0.f, pn = 0.f, qr = 0.f, qz = 0.f, qn = 0.f;
#pragma unroll
  for (int ks = 0; ks < 4; ++ks) {
    const float* P0 = Ppart + (size_t)ks * 393216 + r3;
    const float* P1 = Ppart + (size_t)(4 + ks) * 393216 + r3;
    pr += P0[c]; pz += P0[1024 + c]; pn += P0[2048 + c];
    qr += P1[c]; qz += P1[1024 + c]; qn += P1[2048 + c];
  }
  const u16* gi = gi0_t + r3;
  const float h0 = gru_gate(bf2f(gi[c]) + pr, bf2f(gi[1024 + c]) + pz,
                            bf2f(gi[2048 + c]) + pn, qr + bhh0[c],
                            qz + bhh0[1024 + c], qn + bhh0[2048 + c], h0f[i]);
  h0f[i] = h0;
  const u16 hb = f2bf(h0);
  const u16 lb = f2bf(h0 - bf2f(hb));
  h0a3[r3 + c] = hb;
  h0a3[r3 + 1024 + c] = lb;
  h0a3[r3 + 2048 + c] = hb;
}

__global__ __launch_bounds__(256) void attn_red(
    const float* __restrict__ G1ip, const float* __restrict__ Ppart,
    const float* __restrict__ bih1, const float* __restrict__ bhh1,
    const float* __restrict__ ctxWa, const float* __restrict__ ctxf,
    float* __restrict__ h1f, u16* __restrict__ h1a3, u16* __restrict__ cat3) {
  __shared__ float sh1[1024];
  __shared__ float red[256];
  __shared__ float ssc[64];
  const int b = blockIdx.x;
  const int tid = threadIdx.x;
  const int k = tid * 4;
  const size_t r3 = (size_t)b * 3072;
  const size_t r1 = (size_t)b * 1024;
  u16* catr = cat3 + (size_t)b * 6144;

  {
    f32x4 ir = {0.f, 0.f, 0.f, 0.f}, iz = ir, in_ = ir;
    f32x4 hr = ir, hz = ir, hn = ir;
#pragma unroll
    for (int ks = 0; ks < 4; ++ks) {
      const float* gi = G1ip + (size_t)ks * 393216 + r3;
      const float* gh = Ppart + (size_t)(8 + ks) * 393216 + r3;
      ir += *(const f32x4*)(gi + k);
      iz += *(const f32x4*)(gi + 1024 + k);
      in_ += *(const f32x4*)(gi + 2048 + k);
      hr += *(const f32x4*)(gh + k);
      hz += *(const f32x4*)(gh + 1024 + k);
      hn += *(const f32x4*)(gh + 2048 + k);
    }
    f32x4 bir = *(const f32x4*)(bih1 + k);
    f32x4 biz = *(const f32x4*)(bih1 + 1024 + k);
    f32x4 bin_ = *(const f32x4*)(bih1 + 2048 + k);
    f32x4 bhr = *(const f32x4*)(bhh1 + k);
    f32x4 bhz = *(const f32x4*)(bhh1 + 1024 + k);
    f32x4 bhn = *(const f32x4*)(bhh1 + 2048 + k);
    f32x4 hp = *(const f32x4*)(h1f + r1 + k);
    f32x4 hnew;
    u16x4 hb, lb;
#pragma unroll
    for (int j = 0; j < 4; ++j) {
      hnew[j] = gru_gate(ir[j] + bir[j], iz[j] + biz[j], in_[j] + bin_[j],
                         hr[j] + bhr[j], hz[j] + bhz[j], hn[j] + bhn[j], hp[j]);
      sh1[k + j] = hnew[j];
      hb[j] = f2bf(hnew[j]);
      lb[j] = f2bf(hnew[j] - bf2f(hb[j]));
    }
    *(f32x4*)(h1f + r1 + k) = hnew;
    *(u16x4*)(h1a3 + r3 + k) = hb;
    *(u16x4*)(h1a3 + r3 + 1024 + k) = lb;
    *(u16x4*)(h1a3 + r3 + 2048 + k) = hb;
    *(u16x4*)(catr + 1024 + k) = hb;
    *(u16x4*)(catr + 2048 + 1024 + k) = lb;
    *(u16x4*)(catr + 4096 + 1024 + k) = hb;
  }
  __syncthreads();

  const int s = tid >> 2, part = tid & 3;
  {
    const float* cw = ctxWa + ((size_t)b * 64 + s) * 1024 + part * 256;
    const float* hh = sh1 + part * 256;
    float p = 0.f;
    for (int i = 0; i < 256; i += 4) {
      f32x4 v = *(const f32x4*)(cw + i);
      p += v[0] * hh[i] + v[1] * hh[i + 1] + v[2] * hh[i + 2] +
           v[3] * hh[i + 3];
    }
    red[tid] = p;
  }
  __syncthreads();
  if (part == 0) ssc[s] = red[tid] + red[tid + 1] + red[tid + 2] + red[tid + 3];
  __syncthreads();
  if (tid == 0) {
    float mx = -1e30f;
    for (int i = 0; i < 64; ++i) mx = fmaxf(mx, ssc[i]);
    float sm = 0.f;
    for (int i = 0; i < 64; ++i) {
      float e = expf(ssc[i] - mx);
      ssc[i] = e;
      sm += e;
    }
    const float inv = 1.0f / sm;
    for (int i = 0; i < 64; ++i) ssc[i] *= inv;
  }
  __syncthreads();
  {
    float a0 = 0.f, a1 = 0.f, a2 = 0.f, a3 = 0.f;
    const float* cb = ctxf + (size_t)b * 65536 + k;
    for (int s2 = 0; s2 < 64; ++s2) {
      const float w = ssc[s2];
      f32x4 v = *(const f32x4*)(cb + (size_t)s2 * 1024);
      a0 += w * v[0]; a1 += w * v[1]; a2 += w * v[2]; a3 += w * v[3];
    }
    f32x4 cv{a0, a1, a2, a3};
    u16x4 ch, cl;
#pragma unroll
    for (int j = 0; j < 4; ++j) {
      ch[j] = f2bf(cv[j]);
      cl[j] = f2bf(cv[j] - bf2f(ch[j]));
    }
    *(u16x4*)(catr + k) = ch;
    *(u16x4*)(catr + 2048 + k) = cl;
    *(u16x4*)(catr + 4096 + k) = ch;
  }
}

__global__ __launch_bounds__(256) void out_red(
    const float* __restrict__ Wcpart, float* __restrict__ outf,
    u16* __restrict__ outall_t, u16* __restrict__ out3) {
  const int i = blockIdx.x * 256 + threadIdx.x;  // 131072
  const int b = i >> 10, c = i & 1023;
  float v = 0.f;
#pragma unroll
  for (int ks = 0; ks < 16; ++ks) v += Wcpart[(size_t)ks * 131072 + i];
  const float o = tanhf(v);
  outf[i] = o;
  outall_t[i] = f2bf(o);
  const u16 hb = f2bf(o);
  const u16 lb = f2bf(o - bf2f(hb));
  u16* d = out3 + (size_t)b * 3072;
  d[c] = hb;
  d[1024 + c] = lb;
  d[2048 + c] = hb;
}

__global__ __launch_bounds__(256) void final_copy(
    const float* __restrict__ h0f, const float* __restrict__ h1f,
    const float* __restrict__ outf, float* __restrict__ dst) {
  const int i = blockIdx.x * 256 + threadIdx.x;
  if (i < 131072) dst[i] = h0f[i];
  else if (i < 262144) dst[i] = h1f[i - 131072];
  else if (i < 393216) dst[i] = outf[i - 262144];
}

// ---------------------------------------------------------------------------
extern "C" void kernel_launch(void* const* d_in, const int* in_sizes, int n_in,
                              void* d_out, int out_size, void* d_ws,
                              size_t ws_size, hipStream_t stream) {
  (void)in_sizes; (void)n_in; (void)out_size; (void)ws_size;
  const int* word_ids = (const int*)d_in[0];
  const int* field_ids = (const int*)d_in[1];
  const float* hidden = (const float*)d_in[3];
  const float* context = (const float*)d_in[4];
  const float* prev_output = (const float*)d_in[6];
  const float* wtab = (const float*)d_in[7];
  const float* ftab = (const float*)d_in[8];
  const float* W0ih = (const float*)d_in[9];
  const float* W0hh = (const float*)d_in[10];
  const float* b0ih = (const float*)d_in[11];
  const float* b0hh = (const float*)d_in[12];
  const float* W1ih = (const float*)d_in[13];
  const float* W1hh = (const float*)d_in[14];
  const float* b1ih = (const float*)d_in[15];
  const float* b1hh = (const float*)d_in[16];
  const float* Wa = (const float*)d_in[17];
  const float* Wc = (const float*)d_in[18];
  const float* Ww = (const float*)d_in[19];
  const float* bw = (const float*)d_in[20];
  const float* Wf = (const float*)d_in[21];
  const float* bfb = (const float*)d_in[22];

  char* p = (char*)d_ws;
  auto take = [&](size_t bytes) {
    char* r = p;
    p += (bytes + 255) & ~(size_t)255;
    return r;
  };
  u16* W0ih_b = (u16*)take(3072ull * 1600 * 2);
  u16* W0ihO3 = (u16*)take(3072ull * 3072 * 2);
  u16* W0hh3 = (u16*)take(3072ull * 3072 * 2);
  u16* W1ih3 = (u16*)take(3072ull * 3072 * 2);
  u16* W1hh3 = (u16*)take(3072ull * 3072 * 2);
  u16* WaT3 = (u16*)take(1024ull * 3072 * 2);
  u16* Wc3 = (u16*)take(1024ull * 6144 * 2);
  u16* Ww_b = (u16*)take(32000ull * 1024 * 2);
  u16* Wf_b = (u16*)take(512ull * 1024 * 2);
  u16* ctx3 = (u16*)take(8192ull * 3072 * 2);
  float* ctxWa_f = (float*)take(8192ull * 1024 * 4);
  u16* Xwf_b = (u16*)take(4096ull * 576 * 2);
  u16* gi0_all_b = (u16*)take(4096ull * 3072 * 2);
  u16* outall_b = (u16*)take(32ull * 128 * 1024 * 2);
  u16* out3 = (u16*)take(128ull * 3072 * 2);
  float* h0f = (float*)take(128ull * 1024 * 4);
  float* h1f = (float*)take(128ull * 1024 * 4);
  float* outf = (float*)take(128ull * 1024 * 4);
  u16* h0a3 = (u16*)take(128ull * 3072 * 2);
  u16* h1a3 = (u16*)take(128ull * 3072 * 2);
  u16* cat3 = (u16*)take(128ull * 6144 * 2);
  float* Ppart = (float*)take(12ull * 128 * 3072 * 4);   // 0-3 P, 4-7 G0h, 8-11 G1h
  float* G1ip = (float*)take(4ull * 128 * 3072 * 4);     // planes 0-3
  float* Wcpart = (float*)take(16ull * 128 * 1024 * 4);  // planes 0-15

  // ---- prologue ---------------------------------------------------------
  cvt_bf16_vec<<<dim3(2048), 256, 0, stream>>>(W0ih, W0ih_b, 4915200 / 4);
  split3_w4<<<dim3(12288, 4), 256, 0, stream>>>(W0ih, W0hh, W1ih, W1hh,
                                                W0ihO3, W0hh3, W1ih3, W1hh3);
  split3<true><<<dim3(8192), 256, 0, stream>>>(Wc, 2048, 0, Wc3, 2048,
                                               2097152);
  split3<false><<<dim3(32768), 256, 0, stream>>>(context, 1024, 0, ctx3, 1024,
                                                 8388608);
  transpose_split3<<<dim3(4096), 256, 0, stream>>>(Wa, WaT3);
  cvt_bf16_vec<<<dim3(2048), 256, 0, stream>>>(Ww, Ww_b, 32768000 / 4);
  cvt_bf16_vec<<<dim3(2048), 256, 0, stream>>>(Wf, Wf_b, 524288 / 4);
  gather_emb<<<dim3(4096), 256, 0, stream>>>(word_ids, field_ids, wtab, ftab,
                                             Xwf_b);
  init_state<<<dim3(512), 256, 0, stream>>>(hidden, prev_output, h0f, h1f,
                                            h0a3, h1a3, out3);

  // gi0_wf[t] = Xwf @ W0ih[:, :576]^T + bih0  (bf16 out, plain)
  {
    GemmB3 a{};
    a.A[0] = Xwf_b; a.B[0] = W0ih_b; a.C[0] = gi0_all_b; a.ldb[0] = 1600;
    gemm_bt<128, 128, 1, true><<<dim3(768, 1), 256, 0, stream>>>(
        a, 576, 3072, 24, 576, b0ih, 0);
  }
  // ctxWa = context @ Wa (split-triple, f32 out)
  {
    GemmB3 a{};
    a.A[0] = ctx3; a.B[0] = WaT3; a.C[0] = ctxWa_f; a.ldb[0] = 3072;
    gemm_bt<128, 128, 0, false><<<dim3(512, 1), 256, 0, stream>>>(
        a, 3072, 1024, 8, 3072, nullptr, 0);
  }
  // seed G0h(0) = h0_init @ W0hh -> Ppart planes 4-7
  {
    GemmP a{};
    a.A[0] = h0a3; a.B[0] = W0hh3; a.C[0] = Ppart + 4ull * 393216;
    gemm_part<128, 64><<<dim3(192, 1), 256, 0, stream>>>(
        a, 3072, 3072, 3072, 48, 4, 12, 128);
  }

  // ---- decode loop: 6 launches/step, KS=4 on 3072-K GEMMs ---------------
  for (int t = 0; t < 32; ++t) {
    {
      // GEMM1: {P(t) -> planes 0-3, G1h(t) -> planes 8-11}
      GemmP a{};
      a.A[0] = out3;  a.B[0] = W0ihO3; a.C[0] = Ppart;
      a.A[1] = h1a3;  a.B[1] = W1hh3;  a.C[1] = Ppart + 8ull * 393216;
      gemm_part<128, 64><<<dim3(192, 2), 256, 0, stream>>>(
          a, 3072, 3072, 3072, 48, 4, 12, 128);
    }
    gate0_red<<<dim3(512), 256, 0, stream>>>(
        Ppart, gi0_all_b + (size_t)t * 393216, b0hh, h0f, h0a3);
    {
      // GEMM2: {G1i(t) -> G1ip, G0h(t+1) -> Ppart planes 4-7}
      GemmP a{};
      a.A[0] = h0a3; a.B[0] = W1ih3; a.C[0] = G1ip;
      a.A[1] = h0a3; a.B[1] = W0hh3; a.C[1] = Ppart + 4ull * 393216;
      gemm_part<128, 64><<<dim3(192, 2), 256, 0, stream>>>(
          a, 3072, 3072, 3072, 48, 4, 12, 128);
    }
    attn_red<<<dim3(128), 256, 0, stream>>>(G1ip, Ppart, b1ih, b1hh, ctxWa_f,
                                            context, h1f, h1a3, cat3);
    {
      // GEMM3: Wc(t), tiles 2x16, Ksplit16, K=6144
      GemmP a{};
      a.A[0] = cat3; a.B[0] = Wc3; a.C[0] = Wcpart;
      gemm_part<64, 64><<<dim3(512, 1), 256, 0, stream>>>(
          a, 6144, 6144, 1024, 16, 16, 6, 128);
    }
    out_red<<<dim3(512), 256, 0, stream>>>(
        Wcpart, outf, outall_b + (size_t)t * 131072, out3);
  }

  // ---- generator (time-chunked tile order + gload_lds staging) ----------
  {
    GemmB3 a{};
    a.A[0] = outall_b; a.B[0] = Ww_b; a.C[0] = d_out; a.ldb[0] = 1024;
    gemm_bt<128, 128, 0, true><<<dim3(8000, 1), 256, 0, stream>>>(
        a, 1024, 32000, 250, 1024, bw, 2);
  }
  {
    GemmB3 a{};
    a.A[0] = outall_b; a.B[0] = Wf_b;
    a.C[0] = (float*)d_out + 131072000ull; a.ldb[0] = 1024;
    gemm_bt<128, 128, 0, true><<<dim3(128, 1), 256, 0, stream>>>(
        a, 1024, 512, 4, 1024, bfb, 0);
  }
  final_copy<<<dim3(1536), 256, 0, stream>>>(
      h0f, h1f, outf, (float*)d_out + 133169152ull);
}